// Round 8
// baseline (158.806 us; speedup 1.0000x reference)
//
#include <hip/hip_runtime.h>

// SobelLoss: mean over 3 dirs of mean |sobel(moved) - sobel(label)|.
// conv(m)-conv(l) = conv(m-l); separable: s=[1,2,1], d=[-1,0,1]:
//   gx = sH(dW) rolled sD;  gy = dH(sW) rolled sD;  gz = sH(sW) rolled -dD.
// R8: single-wave blocks (64 thr, zero barriers, zero LDS), prefetch
// depth 2 (3 rotating register plane buffers), DC=10. R7 (~38 us) was
// latency-limited: R6 counters showed occupancy was GRID-limited (4.5
// blocks/CU, 4-wave quantum) and depth-1 prefetch (~350 cyc) < HBM
// latency (~900 cyc). Floors: HBM ~95 MB -> 15 us; VALU ~6 us.
// HARD-WON RULES (R2/R4): no __launch_bounds__ min-waves clamp (spills
// the rolling window -> 200-480 MB scratch traffic).

#define BB 2
#define DD 160
#define HH 192
#define WW 160
#define HW (HH * WW)

#define TH 4                    // output H rows per thread
#define DC 10                   // output D planes per wave
#define NIT (DC + 2)            // 12
#define NTHREADS 64             // ONE wave per block

__global__ __launch_bounds__(NTHREADS) void sobel_loss_kernel(
    const float* __restrict__ moved, const float* __restrict__ label,
    float* __restrict__ out)
{
    const int lane  = threadIdx.x;              // 0..63
    const int wch   = blockIdx.x % 3;           // W chunk: 62 outputs each
    const int htile = blockIdx.x / 3;           // 0..47
    const int hbase = htile * TH;               // 0..188
    const int d0    = blockIdx.y * DC;          // 16 chunks
    const int base_b = blockIdx.z * (DD * HW);

    // lane l holds column w = w0 + l - 1; outputs live on lanes 1..62
    const int  w0 = wch * 62;                   // 0, 62, 124
    const int  w  = w0 + lane - 1;              // -1 .. 186
    const bool wv = (unsigned)w < (unsigned)WW;
    const int  gw = min(max(w, 0), WW - 1);
    const bool outv = (lane >= 1) && (lane <= 62) && (w < WW);

    // per-row constants (fixed across all D iterations)
    int  rowOff[TH + 2];
    bool rv[TH + 2];
#pragma unroll
    for (int r = 0; r < TH + 2; ++r) {
        const int gh = hbase - 1 + r;
        rv[r] = (unsigned)gh < (unsigned)HH;
        rowOff[r] = min(max(gh, 0), HH - 1) * WW + gw;
    }

    // three rotating plane buffers: cur (p), nxt (p+1), nx2 (p+2)
    float mc[TH + 2], lc[TH + 2], mn[TH + 2], ln[TH + 2], m2[TH + 2], l2[TH + 2];
    {
        const int pb0 = base_b + max(d0 - 1, 0) * HW;   // plane d0-1 (clamped)
        const int pb1 = base_b + d0 * HW;               // plane d0 (always valid)
#pragma unroll
        for (int r = 0; r < TH + 2; ++r) {
            mc[r] = moved[pb0 + rowOff[r]];
            lc[r] = label[pb0 + rowOff[r]];
            mn[r] = moved[pb1 + rowOff[r]];
            ln[r] = label[pb1 + rowOff[r]];
        }
    }

    float px1[TH], px2[TH], py1[TH], py2[TH], pz1[TH], pz2[TH];
#pragma unroll
    for (int i = 0; i < TH; ++i) {
        px1[i] = px2[i] = 0.f;
        py1[i] = py2[i] = 0.f;
        pz1[i] = pz2[i] = 0.f;
    }
    float acc = 0.f;

#pragma unroll
    for (int it = 0; it < NIT; ++it) {
        // ---- issue plane p+2 loads; consumed two iterations from now ----
        if (it + 2 < NIT) {
            const int pb = base_b + min(d0 + it + 1, DD - 1) * HW;
#pragma unroll
            for (int r = 0; r < TH + 2; ++r) {
                m2[r] = moved[pb + rowOff[r]];
                l2[r] = label[pb + rowOff[r]];
            }
        }

        // ---- compute on current plane p = d0-1+it ----
        const bool pv = (unsigned)(d0 - 1 + it) < (unsigned)DD;
        float sW[TH + 2], dW[TH + 2];
#pragma unroll
        for (int r = 0; r < TH + 2; ++r) {
            const float d  = (pv && rv[r] && wv) ? (mc[r] - lc[r]) : 0.f;
            const float dl = __shfl_up(d, 1, 64);    // w-1 (lane 0 junk, masked)
            const float dr = __shfl_down(d, 1, 64);  // w+1 (lane 63 junk, masked)
            sW[r] = (dl + dr) + 2.f * d;   // W-smooth
            dW[r] = dr - dl;               // W-deriv
        }
#pragma unroll
        for (int i = 0; i < TH; ++i) {
            const float px = (dW[i] + dW[i + 2]) + 2.f * dW[i + 1];  // sH(dW)
            const float pz = (sW[i] + sW[i + 2]) + 2.f * sW[i + 1];  // sH(sW)
            const float py = sW[i + 2] - sW[i];                      // dH(sW)
            if (it >= 2 && outv) {
                const float gx = px2[i] + 2.f * px1[i] + px;   // sD
                const float gy = py2[i] + 2.f * py1[i] + py;   // sD
                const float gz = pz2[i] - pz;                  // dD: (q-1)-(q+1)
                acc += fabsf(gx) + fabsf(gy) + fabsf(gz);
            }
            px2[i] = px1[i]; px1[i] = px;
            py2[i] = py1[i]; py1[i] = py;
            pz2[i] = pz1[i]; pz1[i] = pz;
        }

        // ---- rotate plane buffers (renamed away by the full unroll) ----
#pragma unroll
        for (int r = 0; r < TH + 2; ++r) {
            mc[r] = mn[r]; lc[r] = ln[r];
            mn[r] = m2[r]; ln[r] = l2[r];
        }
    }

    // ---- wave-level reduce -> one atomic per block (no LDS, no barrier) ----
#pragma unroll
    for (int off = 32; off > 0; off >>= 1)
        acc += __shfl_down(acc, off, 64);
    if (lane == 0)
        atomicAdd(out, acc * (1.0f / (3.0f * BB * DD * HH * WW)));
}

extern "C" void kernel_launch(void* const* d_in, const int* in_sizes, int n_in,
                              void* d_out, int out_size, void* d_ws, size_t ws_size,
                              hipStream_t stream) {
    const float* moved = (const float*)d_in[0];
    const float* label = (const float*)d_in[1];
    float* out = (float*)d_out;
    (void)in_sizes; (void)n_in; (void)out_size; (void)d_ws; (void)ws_size;

    hipMemsetAsync(out, 0, sizeof(float), stream);
    // x: 3 W-chunks * 48 H-tiles; y: 16 D-chunks; z: batch
    dim3 grid(144, DD / DC, BB);    // 4608 one-wave blocks (~18 waves/CU)
    sobel_loss_kernel<<<grid, NTHREADS, 0, stream>>>(moved, label, out);
}

// Round 9
// 134.537 us; speedup vs baseline: 1.1804x; 1.1804x over previous
//
#include <hip/hip_runtime.h>

// SobelLoss: mean over 3 dirs of mean |sobel(moved) - sobel(label)|.
// conv(m)-conv(l) = conv(m-l); separable: s=[1,2,1], d=[-1,0,1]:
//   gx = sH(dW) rolled sD;  gy = dH(sW) rolled sD;  gz = sH(sW) rolled -dD.
// R9: R8's depth-2 register pipeline, fixed. R8 failed twice: single-wave
// blocks hit the 16-workgroup/CU cap (occ 27%), and VGPR_Count=52 proved
// the compiler serialized the prefetch (needs ~90 live regs, default
// heuristic targets ~64). Fix: amdgpu_waves_per_eu(1,4) grants a ~128-VGPR
// budget (4 waves/SIMD = 16 waves/CU target), 2-wave blocks, DC=8,
// 2880 blocks = 5760 waves.
// HARD-WON RULES: no min-waves clamp (R2/R4: spill -> 200-480 MB scratch
// traffic; watch WRITE_SIZE). Wave-uniform DMA predicates (moot: no DMA).

#define BB 2
#define DD 160
#define HH 192
#define WW 160
#define HW (HH * WW)

#define TH 4                    // output H rows per thread
#define DC 8                    // output D planes per wave
#define NIT (DC + 2)            // 10
#define NTHREADS 128            // 2 waves per block, each wave = own H-tile

__global__ __launch_bounds__(NTHREADS)
__attribute__((amdgpu_waves_per_eu(1, 4)))
void sobel_loss_kernel(
    const float* __restrict__ moved, const float* __restrict__ label,
    float* __restrict__ out)
{
    __shared__ float red[2];

    const int tid   = threadIdx.x;
    const int lane  = tid & 63;
    const int wavei = tid >> 6;                 // 0..1
    const int wch   = blockIdx.x % 3;           // W chunk: 62 outputs each
    const int hgrp  = blockIdx.x / 3;           // 0..23
    const int hbase = (hgrp * 2 + wavei) * TH;  // 0..188
    const int d0    = blockIdx.y * DC;          // 20 chunks
    const int base_b = blockIdx.z * (DD * HW);

    // lane l holds column w = w0 + l - 1; outputs live on lanes 1..62
    const int  w0 = wch * 62;                   // 0, 62, 124
    const int  w  = w0 + lane - 1;              // -1 .. 186
    const bool wv = (unsigned)w < (unsigned)WW;
    const int  gw = min(max(w, 0), WW - 1);
    const bool outv = (lane >= 1) && (lane <= 62) && (w < WW);

    // per-row constants (fixed across all D iterations)
    int  rowOff[TH + 2];
    bool rv[TH + 2];
#pragma unroll
    for (int r = 0; r < TH + 2; ++r) {
        const int gh = hbase - 1 + r;
        rv[r] = (unsigned)gh < (unsigned)HH;
        rowOff[r] = min(max(gh, 0), HH - 1) * WW + gw;
    }

    // three rotating plane buffers: cur (p), nxt (p+1), nx2 (p+2)
    float mc[TH + 2], lc[TH + 2], mn[TH + 2], ln[TH + 2], m2[TH + 2], l2[TH + 2];
    {
        const int pb0 = base_b + max(d0 - 1, 0) * HW;   // plane d0-1 (clamped)
        const int pb1 = base_b + d0 * HW;               // plane d0
#pragma unroll
        for (int r = 0; r < TH + 2; ++r) {
            mc[r] = moved[pb0 + rowOff[r]];
            lc[r] = label[pb0 + rowOff[r]];
            mn[r] = moved[pb1 + rowOff[r]];
            ln[r] = label[pb1 + rowOff[r]];
        }
    }

    float px1[TH], px2[TH], py1[TH], py2[TH], pz1[TH], pz2[TH];
#pragma unroll
    for (int i = 0; i < TH; ++i) {
        px1[i] = px2[i] = 0.f;
        py1[i] = py2[i] = 0.f;
        pz1[i] = pz2[i] = 0.f;
    }
    float acc = 0.f;

#pragma unroll
    for (int it = 0; it < NIT; ++it) {
        // ---- issue plane p+2 loads; consumed two iterations from now ----
        if (it + 2 < NIT) {
            const int pb = base_b + min(d0 + it + 1, DD - 1) * HW;
#pragma unroll
            for (int r = 0; r < TH + 2; ++r) {
                m2[r] = moved[pb + rowOff[r]];
                l2[r] = label[pb + rowOff[r]];
            }
        }

        // ---- compute on current plane p = d0-1+it ----
        const bool pv = (unsigned)(d0 - 1 + it) < (unsigned)DD;
        float sW[TH + 2], dW[TH + 2];
#pragma unroll
        for (int r = 0; r < TH + 2; ++r) {
            const float d  = (pv && rv[r] && wv) ? (mc[r] - lc[r]) : 0.f;
            const float dl = __shfl_up(d, 1, 64);    // w-1 (lane 0 junk, masked)
            const float dr = __shfl_down(d, 1, 64);  // w+1 (lane 63 junk, masked)
            sW[r] = (dl + dr) + 2.f * d;   // W-smooth
            dW[r] = dr - dl;               // W-deriv
        }
#pragma unroll
        for (int i = 0; i < TH; ++i) {
            const float px = (dW[i] + dW[i + 2]) + 2.f * dW[i + 1];  // sH(dW)
            const float pz = (sW[i] + sW[i + 2]) + 2.f * sW[i + 1];  // sH(sW)
            const float py = sW[i + 2] - sW[i];                      // dH(sW)
            if (it >= 2 && outv) {
                const float gx = px2[i] + 2.f * px1[i] + px;   // sD
                const float gy = py2[i] + 2.f * py1[i] + py;   // sD
                const float gz = pz2[i] - pz;                  // dD: (q-1)-(q+1)
                acc += fabsf(gx) + fabsf(gy) + fabsf(gz);
            }
            px2[i] = px1[i]; px1[i] = px;
            py2[i] = py1[i]; py1[i] = py;
            pz2[i] = pz1[i]; pz1[i] = pz;
        }

        // ---- rotate plane buffers (renamed away by the full unroll) ----
#pragma unroll
        for (int r = 0; r < TH + 2; ++r) {
            mc[r] = mn[r]; lc[r] = ln[r];
            mn[r] = m2[r]; ln[r] = l2[r];
        }
    }

    // ---- reduce: wave shuffle -> tiny LDS -> one atomic per block ----
#pragma unroll
    for (int off = 32; off > 0; off >>= 1)
        acc += __shfl_down(acc, off, 64);
    if (lane == 0) red[wavei] = acc;
    __syncthreads();
    if (tid == 0)
        atomicAdd(out, (red[0] + red[1]) * (1.0f / (3.0f * BB * DD * HH * WW)));
}

extern "C" void kernel_launch(void* const* d_in, const int* in_sizes, int n_in,
                              void* d_out, int out_size, void* d_ws, size_t ws_size,
                              hipStream_t stream) {
    const float* moved = (const float*)d_in[0];
    const float* label = (const float*)d_in[1];
    float* out = (float*)d_out;
    (void)in_sizes; (void)n_in; (void)out_size; (void)d_ws; (void)ws_size;

    hipMemsetAsync(out, 0, sizeof(float), stream);
    // x: 3 W-chunks * 24 H-groups; y: 20 D-chunks; z: batch
    dim3 grid(72, DD / DC, BB);     // 2880 two-wave blocks = 5760 waves
    sobel_loss_kernel<<<grid, NTHREADS, 0, stream>>>(moved, label, out);
}

// Round 10
// 116.568 us; speedup vs baseline: 1.3623x; 1.1542x over previous
//
#include <hip/hip_runtime.h>

// SobelLoss: mean over 3 dirs of mean |sobel(moved) - sobel(label)|.
// conv(m)-conv(l) = conv(m-l); separable: s=[1,2,1], d=[-1,0,1]:
//   gx = sH(dW) rolled sD;  gy = dH(sW) rolled sD;  gz = sH(sW) rolled -dD.
// R10: hand-pinned depth-2 load pipeline via inline asm. R6-R9 proved the
// HIP scheduler sinks prefetch loads next to use regardless of structure
// or waves_per_eu (VGPR stuck at 40-52, occ<40%, hbm ~20% => exposed
// latency). asm volatile global_load_dword pins issue order and forces
// results live; s_waitcnt vmcnt(24) drains only the oldest plane (12
// loads), keeping 24 loads (6 KB/wave) permanently in flight.
// Buffer regs are tied "+v" on the wait so compute can't hoist above it.
// HARD-WON RULES: no __launch_bounds__ min-waves clamp (R2/R4 spill);
// a spill here would also corrupt vmcnt counting -> watch WRITE_SIZE.

#define BB 2
#define DD 160
#define HH 192
#define WW 160
#define HW (HH * WW)

#define TH 4                    // output H rows per thread
#define DC 8                    // output D planes per wave
#define NIT (DC + 2)            // 10
#define NR (TH + 2)             // 6 rows live per plane
#define NTHREADS 256            // 4 waves/block (R7's best packing)

#define GLOAD(dst, vo, sb) \
    asm volatile("global_load_dword %0, %1, %2" \
                 : "=v"(dst) : "v"(vo), "s"(sb) : "memory")

__global__ __launch_bounds__(NTHREADS)
__attribute__((amdgpu_waves_per_eu(1, 4)))
void sobel_loss_kernel(const float* __restrict__ moved,
                       const float* __restrict__ label,
                       float* __restrict__ out)
{
    __shared__ float red[4];

    const int tid   = threadIdx.x;
    const int lane  = tid & 63;
    const int wavei = tid >> 6;                 // 0..3
    const int wch   = blockIdx.x % 3;           // W chunk: 62 outputs each
    const int hgrp  = blockIdx.x / 3;           // 0..11
    const int hbase = (hgrp * 4 + wavei) * TH;  // 0..188
    const int d0    = blockIdx.y * DC;          // 20 chunks
    const int base_b = blockIdx.z * (DD * HW);

    // lane l holds column w = w0 + l - 1; outputs live on lanes 1..62
    const int  w0 = wch * 62;                   // 0, 62, 124
    const int  w  = w0 + lane - 1;              // -1 .. 186
    const bool wv = (unsigned)w < (unsigned)WW;
    const int  gw = min(max(w, 0), WW - 1);
    const bool outv = (lane >= 1) && (lane <= 62) && (w < WW);

    // per-row byte voffsets (fixed across D); OOB rows clamped, masked later
    int  voff[NR];
    bool rv[NR];
#pragma unroll
    for (int r = 0; r < NR; ++r) {
        const int gh = hbase - 1 + r;
        rv[r] = (unsigned)gh < (unsigned)HH;
        voff[r] = (min(max(gh, 0), HH - 1) * WW + gw) * 4;
    }

    // 3 rotating plane buffers; slot s computed at iters with it%3==s
    float bm[3][NR], bl[3][NR];

    {   // preload slot0 = plane d0-1 (clamped), slot1 = plane d0
        const float* pm = moved + base_b + max(d0 - 1, 0) * HW;
        const float* pl = label + base_b + max(d0 - 1, 0) * HW;
#pragma unroll
        for (int r = 0; r < NR; ++r) {
            GLOAD(bm[0][r], voff[r], pm);
            GLOAD(bl[0][r], voff[r], pl);
        }
        const float* qm = moved + base_b + d0 * HW;
        const float* ql = label + base_b + d0 * HW;
#pragma unroll
        for (int r = 0; r < NR; ++r) {
            GLOAD(bm[1][r], voff[r], qm);
            GLOAD(bl[1][r], voff[r], ql);
        }
    }   // outstanding: 24

    float px1[TH], px2[TH], py1[TH], py2[TH], pz1[TH], pz2[TH];
#pragma unroll
    for (int i = 0; i < TH; ++i) {
        px1[i] = px2[i] = 0.f;
        py1[i] = py2[i] = 0.f;
        pz1[i] = pz2[i] = 0.f;
    }
    float acc = 0.f;

#pragma unroll
    for (int it = 0; it < NIT; ++it) {
        const int s  = it % 3;          // slot to compute (plane d0-1+it)
        const int s2 = (it + 2) % 3;    // slot to issue (plane d0+1+it)

        // ---- issue next-next plane (clamped addr; uniform 12 loads) ----
        {
            const int p = min(d0 + it + 1, DD - 1);
            const float* pm = moved + base_b + p * HW;
            const float* pl = label + base_b + p * HW;
#pragma unroll
            for (int r = 0; r < NR; ++r) {
                GLOAD(bm[s2][r], voff[r], pm);
                GLOAD(bl[s2][r], voff[r], pl);
            }
        }   // outstanding: 36

        // ---- wait ONLY the oldest 12 (slot s); keep 24 in flight.
        //      "+v" ties force compute below to stay below this wait. ----
        asm volatile("s_waitcnt vmcnt(24)"
            : "+v"(bm[s][0]), "+v"(bm[s][1]), "+v"(bm[s][2]),
              "+v"(bm[s][3]), "+v"(bm[s][4]), "+v"(bm[s][5]),
              "+v"(bl[s][0]), "+v"(bl[s][1]), "+v"(bl[s][2]),
              "+v"(bl[s][3]), "+v"(bl[s][4]), "+v"(bl[s][5]));

        // ---- compute plane p = d0-1+it ----
        const bool pv = (unsigned)(d0 - 1 + it) < (unsigned)DD;
        float sW[NR], dW[NR];
#pragma unroll
        for (int r = 0; r < NR; ++r) {
            const float d  = (pv && rv[r] && wv) ? (bm[s][r] - bl[s][r]) : 0.f;
            const float dl = __shfl_up(d, 1, 64);    // w-1 (lane 0 junk, masked)
            const float dr = __shfl_down(d, 1, 64);  // w+1 (lane 63 junk, masked)
            sW[r] = (dl + dr) + 2.f * d;   // W-smooth
            dW[r] = dr - dl;               // W-deriv
        }
#pragma unroll
        for (int i = 0; i < TH; ++i) {
            const float px = (dW[i] + dW[i + 2]) + 2.f * dW[i + 1];  // sH(dW)
            const float pz = (sW[i] + sW[i + 2]) + 2.f * sW[i + 1];  // sH(sW)
            const float py = sW[i + 2] - sW[i];                      // dH(sW)
            if (it >= 2 && outv) {
                const float gx = px2[i] + 2.f * px1[i] + px;   // sD
                const float gy = py2[i] + 2.f * py1[i] + py;   // sD
                const float gz = pz2[i] - pz;                  // dD: (q-1)-(q+1)
                acc += fabsf(gx) + fabsf(gy) + fabsf(gz);
            }
            px2[i] = px1[i]; px1[i] = px;
            py2[i] = py1[i]; py1[i] = py;
            pz2[i] = pz1[i]; pz1[i] = pz;
        }
    }

    // drain the 24 tail loads before reusing the memory pipe / ending
    asm volatile("s_waitcnt vmcnt(0)" ::: "memory");

    // ---- reduce: wave shuffle -> tiny LDS -> one atomic per block ----
#pragma unroll
    for (int off = 32; off > 0; off >>= 1)
        acc += __shfl_down(acc, off, 64);
    if (lane == 0) red[wavei] = acc;
    __syncthreads();
    if (tid == 0) {
        const float s = red[0] + red[1] + red[2] + red[3];
        atomicAdd(out, s * (1.0f / (3.0f * BB * DD * HH * WW)));
    }
}

extern "C" void kernel_launch(void* const* d_in, const int* in_sizes, int n_in,
                              void* d_out, int out_size, void* d_ws, size_t ws_size,
                              hipStream_t stream) {
    const float* moved = (const float*)d_in[0];
    const float* label = (const float*)d_in[1];
    float* out = (float*)d_out;
    (void)in_sizes; (void)n_in; (void)out_size; (void)d_ws; (void)ws_size;

    hipMemsetAsync(out, 0, sizeof(float), stream);
    // x: 3 W-chunks * 12 H-groups; y: 20 D-chunks; z: batch
    dim3 grid(36, DD / DC, BB);     // 1440 four-wave blocks = 5760 waves
    sobel_loss_kernel<<<grid, NTHREADS, 0, stream>>>(moved, label, out);
}